// Round 2
// baseline (443.013 us; speedup 1.0000x reference)
//
#include <hip/hip_runtime.h>
#include <hip/hip_bf16.h>

namespace {

constexpr int V_ = 256, K_ = 32, C_ = 256;
constexpr int N_ = V_ * K_;            // 8192 nodes per layer
constexpr int E_ = 32768, PF_ = 4, SF_ = 16, L_ = 5;
constexpr int B_ = 512;                // batch
constexpr int NCH = 64;                // root partial chunks

// nm[v*K+k][b] = logps[v][k][inputs[b][v]]
__global__ void input_layer_k(const int* __restrict__ inp,   // [B,V]
                              const float* __restrict__ lp,  // [V,K,C]
                              float* __restrict__ nm)        // [N,B]
{
    const int b = blockIdx.y * blockDim.x + threadIdx.x;
    const int v = blockIdx.x;
    const int c = inp[b * V_ + v];
    const float* row = lp + (size_t)v * K_ * C_ + c;
    float* o = nm + (size_t)v * K_ * B_ + b;
    #pragma unroll
    for (int k = 0; k < K_; ++k)
        o[k * B_] = row[k * C_];
}

// em[e][b] = sum_f nm[pc[e][f]][b]
__global__ void prod_k(const float* __restrict__ nm,   // [N,B]
                       const int* __restrict__ pc,     // [E,PF]
                       float* __restrict__ em)         // [E,B]
{
    const int t = blockIdx.x * blockDim.x + threadIdx.x;   // E * B/4 threads
    const int e = t >> 7;            // / (B/4 = 128)
    const int b = (t & 127) << 2;
    const int4 ch = *reinterpret_cast<const int4*>(pc + (size_t)e * 4);
    const float4 a0 = *reinterpret_cast<const float4*>(nm + (size_t)ch.x * B_ + b);
    const float4 a1 = *reinterpret_cast<const float4*>(nm + (size_t)ch.y * B_ + b);
    const float4 a2 = *reinterpret_cast<const float4*>(nm + (size_t)ch.z * B_ + b);
    const float4 a3 = *reinterpret_cast<const float4*>(nm + (size_t)ch.w * B_ + b);
    float4 r;
    r.x = (a0.x + a1.x) + (a2.x + a3.x);
    r.y = (a0.y + a1.y) + (a2.y + a3.y);
    r.z = (a0.z + a1.z) + (a2.z + a3.z);
    r.w = (a0.w + a1.w) + (a2.w + a3.w);
    *reinterpret_cast<float4*>(em + (size_t)e * B_ + b) = r;
}

// nm[n][b] = logsumexp_s( em[sc[n][s]][b] + lw[n][s] )
__global__ void sum_k(const float* __restrict__ em,    // [E,B]
                      const int* __restrict__ sc,      // [N,SF]
                      const float* __restrict__ lw,    // [N,SF]
                      float* __restrict__ nm)          // [N,B]
{
    const int t = blockIdx.x * blockDim.x + threadIdx.x;     // N * B/4 threads
    const int n = t >> 7;
    const int b = (t & 127) << 2;
    float4 x[SF_];
    #pragma unroll
    for (int s = 0; s < SF_; ++s) {
        const int e = sc[(size_t)n * SF_ + s];
        float4 v = *reinterpret_cast<const float4*>(em + (size_t)e * B_ + b);
        const float w = lw[(size_t)n * SF_ + s];
        v.x += w; v.y += w; v.z += w; v.w += w;
        x[s] = v;
    }
    float4 m = x[0];
    #pragma unroll
    for (int s = 1; s < SF_; ++s) {
        m.x = fmaxf(m.x, x[s].x);
        m.y = fmaxf(m.y, x[s].y);
        m.z = fmaxf(m.z, x[s].z);
        m.w = fmaxf(m.w, x[s].w);
    }
    float4 acc = make_float4(0.f, 0.f, 0.f, 0.f);
    #pragma unroll
    for (int s = 0; s < SF_; ++s) {
        acc.x += __expf(x[s].x - m.x);
        acc.y += __expf(x[s].y - m.y);
        acc.z += __expf(x[s].z - m.z);
        acc.w += __expf(x[s].w - m.w);
    }
    float4 r;
    r.x = m.x + __logf(acc.x);
    r.y = m.y + __logf(acc.y);
    r.z = m.z + __logf(acc.z);
    r.w = m.w + __logf(acc.w);
    *reinterpret_cast<float4*>(nm + (size_t)n * B_ + b) = r;
}

// stage 1 of root LSE: per-chunk online logsumexp over n
__global__ void root_part_k(const float* __restrict__ nm,   // [N,B]
                            const float* __restrict__ rw,   // [N]
                            float* __restrict__ pm,         // [NCH,B]
                            float* __restrict__ ps)         // [NCH,B]
{
    const int b = blockIdx.x * blockDim.x + threadIdx.x;
    const int ch = blockIdx.y;
    const int n0 = ch * (N_ / NCH);
    float m = -3.0e38f, s = 0.f;
    for (int i = 0; i < N_ / NCH; ++i) {
        const int n = n0 + i;
        const float x = nm[(size_t)n * B_ + b] + rw[n];
        const float mn = fmaxf(m, x);
        s = s * __expf(m - mn) + __expf(x - mn);
        m = mn;
    }
    pm[ch * B_ + b] = m;
    ps[ch * B_ + b] = s;
}

// stage 2: combine chunk partials
__global__ void root_comb_k(const float* __restrict__ pm,
                            const float* __restrict__ ps,
                            float* __restrict__ out)        // [B]
{
    const int b = blockIdx.x * blockDim.x + threadIdx.x;
    float m = -3.0e38f;
    for (int ch = 0; ch < NCH; ++ch) m = fmaxf(m, pm[ch * B_ + b]);
    float s = 0.f;
    for (int ch = 0; ch < NCH; ++ch) s += ps[ch * B_ + b] * __expf(pm[ch * B_ + b] - m);
    out[b] = m + __logf(s);
}

} // namespace

extern "C" void kernel_launch(void* const* d_in, const int* in_sizes, int n_in,
                              void* d_out, int out_size, void* d_ws, size_t ws_size,
                              hipStream_t stream) {
    const int*   inp = (const int*)d_in[0];     // [B,V]
    const float* lp  = (const float*)d_in[1];   // [V,K,C]
    const int*   pc  = (const int*)d_in[2];     // [L,E,PF]
    const int*   sc  = (const int*)d_in[3];     // [L,N,SF]
    const float* lw  = (const float*)d_in[4];   // [L,N,SF]
    const float* rw  = (const float*)d_in[5];   // [N]
    float*       out = (float*)d_out;           // [B,1]

    float* nm = (float*)d_ws;                       // 8192*512*4  = 16 MB
    float* em = nm + (size_t)N_ * B_;               // 32768*512*4 = 64 MB
    float* pm = em + (size_t)E_ * B_;               // 64*512*4
    float* ps = pm + (size_t)NCH * B_;              // 64*512*4

    input_layer_k<<<dim3(V_, B_ / 256), 256, 0, stream>>>(inp, lp, nm);

    for (int l = 0; l < L_; ++l) {
        prod_k<<<(E_ * (B_ / 4)) / 256, 256, 0, stream>>>(
            nm, pc + (size_t)l * E_ * PF_, em);
        sum_k<<<(N_ * (B_ / 4)) / 256, 256, 0, stream>>>(
            em, sc + (size_t)l * N_ * SF_, lw + (size_t)l * N_ * SF_, nm);
    }

    root_part_k<<<dim3(B_ / 256, NCH), 256, 0, stream>>>(nm, rw, pm, ps);
    root_comb_k<<<B_ / 256, 256, 0, stream>>>(pm, ps, out);
}

// Round 3
// 255.311 us; speedup vs baseline: 1.7352x; 1.7352x over previous
//
#include <hip/hip_runtime.h>
#include <hip/hip_fp16.h>

namespace {

constexpr int V_ = 256, K_ = 32, C_ = 256;
constexpr int N_ = V_ * K_;            // 8192 nodes per layer
constexpr int E_ = 32768, PF_ = 4, SF_ = 16, L_ = 5;
constexpr int B_ = 512;                // batch
constexpr int NCH = 64;                // root partial chunks

__device__ __forceinline__ float2 h2f(uint32_t u) {
    __half2 h = *reinterpret_cast<__half2*>(&u);
    return __half22float2(h);
}
__device__ __forceinline__ uint32_t f2h(float a, float b) {
    __half2 h = __floats2half2_rn(a, b);
    return *reinterpret_cast<uint32_t*>(&h);
}

// nm[v*K+k][b..b+3] = logps[v][k][inputs[b..b+3][v]]   (f16 out)
__global__ void input_layer_k(const int* __restrict__ inp,   // [B,V]
                              const float* __restrict__ lp,  // [V,K,C]
                              uint32_t* __restrict__ nm)     // [N,B] f16, as u32 pairs
{
    const int t = blockIdx.x * blockDim.x + threadIdx.x;  // V*K*(B/4)
    const int b = (t & 127) << 2;
    const int vk = t >> 7;
    const int v = vk >> 5;            // / K
    const float* row = lp + (size_t)vk * C_;
    const int c0 = inp[(b + 0) * V_ + v];
    const int c1 = inp[(b + 1) * V_ + v];
    const int c2 = inp[(b + 2) * V_ + v];
    const int c3 = inp[(b + 3) * V_ + v];
    uint2 r;
    r.x = f2h(row[c0], row[c1]);
    r.y = f2h(row[c2], row[c3]);
    *reinterpret_cast<uint2*>(nm + ((size_t)vk * B_ + b) / 2) = r;
}

// em[e][b..b+3] = sum_f nm[pc[e][f]][b..b+3]
__global__ void prod_k(const uint32_t* __restrict__ nm,  // [N,B] f16
                       const int* __restrict__ pc,       // [E,PF]
                       uint32_t* __restrict__ em)        // [E,B] f16
{
    const int t = blockIdx.x * blockDim.x + threadIdx.x;   // E * B/4
    const int e = t >> 7;
    const int b = (t & 127) << 2;
    const int4 ch = *reinterpret_cast<const int4*>(pc + (size_t)e * 4);
    const uint2 u0 = *reinterpret_cast<const uint2*>(nm + ((size_t)ch.x * B_ + b) / 2);
    const uint2 u1 = *reinterpret_cast<const uint2*>(nm + ((size_t)ch.y * B_ + b) / 2);
    const uint2 u2 = *reinterpret_cast<const uint2*>(nm + ((size_t)ch.z * B_ + b) / 2);
    const uint2 u3 = *reinterpret_cast<const uint2*>(nm + ((size_t)ch.w * B_ + b) / 2);
    const float2 a0 = h2f(u0.x), b0 = h2f(u0.y);
    const float2 a1 = h2f(u1.x), b1 = h2f(u1.y);
    const float2 a2 = h2f(u2.x), b2 = h2f(u2.y);
    const float2 a3 = h2f(u3.x), b3 = h2f(u3.y);
    uint2 r;
    r.x = f2h((a0.x + a1.x) + (a2.x + a3.x), (a0.y + a1.y) + (a2.y + a3.y));
    r.y = f2h((b0.x + b1.x) + (b2.x + b3.x), (b0.y + b1.y) + (b2.y + b3.y));
    *reinterpret_cast<uint2*>(em + ((size_t)e * B_ + b) / 2) = r;
}

// nm[n][b..b+3] = logsumexp_s( em[sc[n][s]][b..b+3] + lw[n][s] )
__global__ void sum_k(const uint32_t* __restrict__ em,   // [E,B] f16
                      const int* __restrict__ sc,        // [N,SF]
                      const float* __restrict__ lw,      // [N,SF]
                      uint32_t* __restrict__ nm)         // [N,B] f16
{
    const int t = blockIdx.x * blockDim.x + threadIdx.x;   // N * B/4
    const int n = t >> 7;
    const int b = (t & 127) << 2;

    int4 scv[4];
    float4 lwv[4];
    #pragma unroll
    for (int q = 0; q < 4; ++q) {
        scv[q] = *reinterpret_cast<const int4*>(sc + (size_t)n * SF_ + q * 4);
        lwv[q] = *reinterpret_cast<const float4*>(lw + (size_t)n * SF_ + q * 4);
    }
    const int* sci = reinterpret_cast<const int*>(scv);
    const float* lwf = reinterpret_cast<const float*>(lwv);

    uint2 xr[SF_];
    #pragma unroll
    for (int s = 0; s < SF_; ++s)
        xr[s] = *reinterpret_cast<const uint2*>(em + ((size_t)sci[s] * B_ + b) / 2);

    // pass 1: max
    float4 m = make_float4(-3.0e38f, -3.0e38f, -3.0e38f, -3.0e38f);
    #pragma unroll
    for (int s = 0; s < SF_; ++s) {
        const float w = lwf[s];
        const float2 lo = h2f(xr[s].x), hi = h2f(xr[s].y);
        m.x = fmaxf(m.x, lo.x + w);
        m.y = fmaxf(m.y, lo.y + w);
        m.z = fmaxf(m.z, hi.x + w);
        m.w = fmaxf(m.w, hi.y + w);
    }
    // pass 2: sum of exp
    float4 acc = make_float4(0.f, 0.f, 0.f, 0.f);
    #pragma unroll
    for (int s = 0; s < SF_; ++s) {
        const float w = lwf[s];
        const float2 lo = h2f(xr[s].x), hi = h2f(xr[s].y);
        acc.x += __expf(lo.x + w - m.x);
        acc.y += __expf(lo.y + w - m.y);
        acc.z += __expf(hi.x + w - m.z);
        acc.w += __expf(hi.y + w - m.w);
    }
    uint2 r;
    r.x = f2h(m.x + __logf(acc.x), m.y + __logf(acc.y));
    r.y = f2h(m.z + __logf(acc.z), m.w + __logf(acc.w));
    *reinterpret_cast<uint2*>(nm + ((size_t)n * B_ + b) / 2) = r;
}

// stage 1 of root LSE: per-chunk online logsumexp over n
__global__ void root_part_k(const __half* __restrict__ nm,  // [N,B] f16
                            const float* __restrict__ rw,   // [N]
                            float* __restrict__ pm,         // [NCH,B]
                            float* __restrict__ ps)         // [NCH,B]
{
    const int b = blockIdx.x * blockDim.x + threadIdx.x;
    const int ch = blockIdx.y;
    const int n0 = ch * (N_ / NCH);
    float m = -3.0e38f, s = 0.f;
    for (int i = 0; i < N_ / NCH; ++i) {
        const int n = n0 + i;
        const float x = __half2float(nm[(size_t)n * B_ + b]) + rw[n];
        const float mn = fmaxf(m, x);
        s = s * __expf(m - mn) + __expf(x - mn);
        m = mn;
    }
    pm[ch * B_ + b] = m;
    ps[ch * B_ + b] = s;
}

// stage 2: combine chunk partials
__global__ void root_comb_k(const float* __restrict__ pm,
                            const float* __restrict__ ps,
                            float* __restrict__ out)        // [B]
{
    const int b = blockIdx.x * blockDim.x + threadIdx.x;
    float m = -3.0e38f;
    for (int ch = 0; ch < NCH; ++ch) m = fmaxf(m, pm[ch * B_ + b]);
    float s = 0.f;
    for (int ch = 0; ch < NCH; ++ch) s += ps[ch * B_ + b] * __expf(pm[ch * B_ + b] - m);
    out[b] = m + __logf(s);
}

} // namespace

extern "C" void kernel_launch(void* const* d_in, const int* in_sizes, int n_in,
                              void* d_out, int out_size, void* d_ws, size_t ws_size,
                              hipStream_t stream) {
    const int*   inp = (const int*)d_in[0];     // [B,V]
    const float* lp  = (const float*)d_in[1];   // [V,K,C]
    const int*   pc  = (const int*)d_in[2];     // [L,E,PF]
    const int*   sc  = (const int*)d_in[3];     // [L,N,SF]
    const float* lw  = (const float*)d_in[4];   // [L,N,SF]
    const float* rw  = (const float*)d_in[5];   // [N]
    float*       out = (float*)d_out;           // [B,1]

    uint32_t* nm = (uint32_t*)d_ws;                      // 8192*512*2  = 8 MB (f16)
    uint32_t* em = nm + (size_t)N_ * B_ / 2;             // 32768*512*2 = 32 MB (f16)
    float*    pm = (float*)(em + (size_t)E_ * B_ / 2);   // 64*512*4
    float*    ps = pm + (size_t)NCH * B_;                // 64*512*4

    input_layer_k<<<(V_ * K_ * (B_ / 4)) / 256, 256, 0, stream>>>(inp, lp, nm);

    for (int l = 0; l < L_; ++l) {
        prod_k<<<(E_ * (B_ / 4)) / 256, 256, 0, stream>>>(
            nm, pc + (size_t)l * E_ * PF_, em);
        sum_k<<<(N_ * (B_ / 4)) / 256, 256, 0, stream>>>(
            em, sc + (size_t)l * N_ * SF_, lw + (size_t)l * N_ * SF_, nm);
    }

    root_part_k<<<dim3(B_ / 256, NCH), 256, 0, stream>>>((const __half*)nm, rw, pm, ps);
    root_comb_k<<<B_ / 256, 256, 0, stream>>>(pm, ps, out);
}